// Round 2
// baseline (392.894 us; speedup 1.0000x reference)
//
#include <hip/hip_runtime.h>
#include <math.h>

#define BATCH 16
#define P 32768
#define C 81
#define CM1 80
#define NCAND 400
#define NOUT 100
#define NBINS 256
#define SMIN_F (-3.0f)
#define BIN_SCALE (NBINS / 3.0f)
#define SORTN 1024
#define IMG_SZ 512.0f
#define NMS_THR 0.45f
#define NWORDS 7
#define NPAD 448
#define RPB 64        // rows per block in the streaming pass
#define LCAP 2048     // per-block candidate staging (expected ~150, 13+ sigma headroom)
#define CAND_CAP 131072  // per-image global candidate cap (expected ~76K)

// ---- workspace layout (bytes) ----
#define OFF_HIST 0                               // BATCH*NBINS*4 = 16384
#define OFF_GCNT 16384                           // BATCH*4 = 64
#define OFF_CAND 16448                           // BATCH*CAND_CAP*8 = 16 MB
#define NEED_WS (OFF_CAND + (size_t)BATCH * CAND_CAP * 8)

__device__ __forceinline__ int score_bin(float sc) {
    int b = (int)((sc - SMIN_F) * BIN_SCALE);
    return b < 0 ? 0 : (b > NBINS - 1 ? NBINS - 1 : b);
}

// Quad-per-row stats: lane q of a 4-lane quad holds columns c = 4k+q,
// reductions via xor-1/xor-2. Single site now (scores computed once, in k_hist).
__device__ __forceinline__ void quad_stats(const float* __restrict__ rowp, int q,
                                           float r[21], float& m, float& l, float& fg) {
#pragma unroll
    for (int k = 0; k < 21; ++k) {
        int c = 4 * k + q;
        r[k] = (c < C) ? rowp[c] : -INFINITY;
    }
    float mm = -INFINITY;
#pragma unroll
    for (int k = 0; k < 21; ++k) mm = fmaxf(mm, r[k]);
    mm = fmaxf(mm, __shfl_xor(mm, 1));
    mm = fmaxf(mm, __shfl_xor(mm, 2));
    float s = 0.0f;
#pragma unroll
    for (int k = 0; k < 21; ++k) {
        int c = 4 * k + q;
        if (c < C) s += __expf(r[k] - mm);
    }
    s += __shfl_xor(s, 1);
    s += __shfl_xor(s, 2);
    float fgm = -INFINITY;
#pragma unroll
    for (int k = 0; k < 21; ++k) {
        int c = 4 * k + q;
        if (c >= 1 && c < C) fgm = fmaxf(fgm, r[k]);
    }
    fgm = fmaxf(fgm, __shfl_xor(fgm, 1));
    fgm = fmaxf(fgm, __shfl_xor(fgm, 2));
    m = mm;
    l = __logf(s);
    fg = fgm;
}

// Monotone-decreasing-in-value, unique (id in low bits) sort key.
// pack/unpack is an exact involution on the float bits.
__device__ __forceinline__ unsigned long long pack_key(float v, unsigned id) {
    unsigned bits = __float_as_uint(v);
    unsigned u = (bits & 0x80000000u) ? ~bits : (bits | 0x80000000u);
    return ((unsigned long long)(~u) << 32) | id;  // asc key == desc value, asc idx
}

__device__ __forceinline__ float unpack_score(unsigned long long kk) {
    unsigned uu = ~(unsigned)(kk >> 32);
    unsigned bits = (uu & 0x80000000u) ? (uu & 0x7FFFFFFFu) : ~uu;
    return __uint_as_float(bits);
}

// ---- pass 1: linear float4 staging into LDS, quad-per-row stats,
// histogram of scores > SMIN_F + direct candidate-list emission.
__global__ __launch_bounds__(256) void k_hist(const float* __restrict__ logits,
                                              unsigned* __restrict__ hist,
                                              unsigned* __restrict__ gcnt,
                                              unsigned long long* __restrict__ cand) {
    __shared__ float tile[RPB * C];          // 20736 B
    __shared__ unsigned lh[NBINS];           // 1 KB
    __shared__ unsigned long long lc[LCAP];  // 16 KB
    __shared__ int lcnt_sh;
    __shared__ int base_sh;
    int img = blockIdx.y;
    int row0 = blockIdx.x * RPB;
    lh[threadIdx.x] = 0;
    if (threadIdx.x == 0) lcnt_sh = 0;
    const float4* g4 = (const float4*)(logits + ((size_t)img * P + row0) * C);
    float4* t4 = (float4*)tile;
#pragma unroll
    for (int i = 0; i < 6; ++i) {
        int idx = threadIdx.x + i * 256;
        if (idx < RPB * C / 4) t4[idx] = g4[idx];
    }
    __syncthreads();
    int quad = threadIdx.x >> 2, q = threadIdx.x & 3;
    const float* rowp = tile + quad * C;
    float r[21], m, l, fg;
    quad_stats(rowp, q, r, m, l, fg);
    (void)fg;
    int row = row0 + quad;
#pragma unroll
    for (int k = 0; k < 21; ++k) {
        int c = 4 * k + q;
        if (c >= 1 && c < C) {
            float sc = (r[k] - m) - l;
            if (sc > SMIN_F) {
                atomicAdd(&lh[score_bin(sc)], 1u);
                int pos = atomicAdd(&lcnt_sh, 1);
                if (pos < LCAP) lc[pos] = pack_key(sc, (unsigned)(row * CM1 + c - 1));
            }
        }
    }
    __syncthreads();
    unsigned h = lh[threadIdx.x];
    if (h) atomicAdd(&hist[(size_t)img * NBINS + threadIdx.x], h);
    int n = lcnt_sh;
    if (n > LCAP) n = LCAP;
    if (threadIdx.x == 0) base_sh = (int)atomicAdd(&gcnt[img], (unsigned)n);
    __syncthreads();
    int base = base_sh;
    unsigned long long* dst = cand + (size_t)img * CAND_CAP;
    for (int i = threadIdx.x; i < n; i += 256) {
        int pos = base + i;
        if (pos < CAND_CAP) dst[pos] = lc[i];
    }
}

// ---- pass 2: one block per image, 1024 threads (16 waves).
// threshold -> filter candidate list -> register bitonic sort -> decode ->
// IoU -> greedy NMS -> outputs.
__global__ __launch_bounds__(1024) void k_post(const float* __restrict__ bbox,
                                               const float* __restrict__ priors,
                                               const unsigned* __restrict__ hist,
                                               const unsigned* __restrict__ gcnt,
                                               const unsigned long long* __restrict__ cand,
                                               float* __restrict__ out) {
    __shared__ int tb_sh, ncand_sh;
    __shared__ unsigned long long key[SORTN];
    __shared__ float x1[NCAND], y1[NCAND], x2[NCAND], y2[NCAND];
    __shared__ float ox1[NPAD], oy1[NPAD], ox2[NPAD], oy2[NPAD], areas[NPAD];
    __shared__ float scs[NCAND];
    __shared__ int lab[NCAND];
    __shared__ unsigned long long M[NPAD][NWORDS];
    __shared__ unsigned long long keepw_s[NWORDS];
    __shared__ int wpre_s[NWORDS + 1];
    __shared__ float wred[16];
    __shared__ float maxc_sh;
    __shared__ int kidx[NOUT];

    int img = blockIdx.x;
    int tid = threadIdx.x;
    int lane = tid & 63;
    int wv = tid >> 6;

    if (tid == 0) { tb_sh = 0; ncand_sh = 0; }
    key[tid] = pack_key(-INFINITY, 0x7FFFFFFFu);

    // wave 0: histogram suffix-scan -> threshold bin (exact unsigned sums).
    if (wv == 0) {
        uint4 h4 = ((const uint4*)(hist + (size_t)img * NBINS))[lane];
        unsigned own = h4.x + h4.y + h4.z + h4.w;
        unsigned acc = own;
#pragma unroll
        for (int off = 1; off < 64; off <<= 1) {
            unsigned t = __shfl_down(acc, off);
            if (lane + off < 64) acc += t;
        }
        unsigned above = acc - own;        // sum of bins >= 4*(lane+1)
        unsigned s3 = above + h4.w;        // suffix(4*lane+3)
        unsigned s2 = s3 + h4.z;
        unsigned s1 = s2 + h4.y;
        unsigned s0 = s1 + h4.x;           // suffix(4*lane)
        int best = -1;
        if (s0 >= NCAND) best = 4 * lane + 0;
        if (s1 >= NCAND) best = 4 * lane + 1;
        if (s2 >= NCAND) best = 4 * lane + 2;
        if (s3 >= NCAND) best = 4 * lane + 3;
#pragma unroll
        for (int off = 32; off >= 1; off >>= 1) {
            int o = __shfl_xor(best, off);
            best = best > o ? best : o;
        }
        if (lane == 0) tb_sh = best < 0 ? 0 : best;
    }
    __syncthreads();
    int tb = tb_sh;

    // stream the per-image candidate list; keep bin >= tb.
    // Same set as old filter (list holds exactly the sc > SMIN_F elements,
    // unpack is bit-exact -> identical score_bin); unique keys + full sort
    // make append order irrelevant.
    {
        int n = (int)gcnt[img];
        if (n > CAND_CAP) n = CAND_CAP;
        const unsigned long long* src = cand + (size_t)img * CAND_CAP;
        for (int i = tid; i < n; i += 1024) {
            unsigned long long kk = src[i];
            if (score_bin(unpack_score(kk)) >= tb) {
                int pos = atomicAdd(&ncand_sh, 1);
                if (pos < SORTN) key[pos] = kk;
            }
        }
    }
    __syncthreads();

    // register-resident bitonic sort, ascending on u64 keys.
    // thread t owns element t. j<=32 phases are intra-wave (shfl_xor, no
    // barrier) - 45 of 55 phases. Only j>=64 phases exchange through LDS.
    unsigned long long kr = key[tid];
#pragma unroll
    for (int k2 = 2; k2 <= 64; k2 <<= 1) {
        for (int j = k2 >> 1; j > 0; j >>= 1) {
            unsigned long long pv = __shfl_xor(kr, j);
            bool takeMin = (((tid & j) == 0) == ((tid & k2) == 0));
            bool sel = takeMin ? (pv < kr) : (pv > kr);
            if (sel) kr = pv;
        }
    }
    for (int k2 = 128; k2 <= SORTN; k2 <<= 1) {
        for (int j = k2 >> 1; j >= 64; j >>= 1) {
            __syncthreads();   // prior phase's reads done before overwrite
            key[tid] = kr;
            __syncthreads();
            unsigned long long pv = key[tid ^ j];
            bool takeMin = (((tid & j) == 0) == ((tid & k2) == 0));
            bool sel = takeMin ? (pv < kr) : (pv > kr);
            if (sel) kr = pv;
        }
#pragma unroll
        for (int j = 32; j > 0; j >>= 1) {
            unsigned long long pv = __shfl_xor(kr, j);
            bool takeMin = (((tid & j) == 0) == ((tid & k2) == 0));
            bool sel = takeMin ? (pv < kr) : (pv > kr);
            if (sel) kr = pv;
        }
    }

    // decode top-400 (element tid lives in thread tid's register)
    if (tid < NCAND) {
        scs[tid] = unpack_score(kr);
        unsigned f = (unsigned)(kr & 0xFFFFFFFFu);
        if (f > (unsigned)(P * CM1 - 1)) f = (unsigned)(P * CM1 - 1);
        int p = (int)(f / CM1);
        int c = (int)(f % CM1) + 1;
        const float* lp = bbox + ((size_t)img * P + p) * 4;
        const float* pp = priors + (size_t)p * 4;
        float cx = lp[0] * 0.1f * pp[2] + pp[0];
        float cy = lp[1] * 0.1f * pp[3] + pp[1];
        float w = expf(lp[2] * 0.2f) * pp[2];
        float h = expf(lp[3] * 0.2f) * pp[3];
        x1[tid] = (cx - w * 0.5f) * IMG_SZ;
        y1[tid] = (cy - h * 0.5f) * IMG_SZ;
        x2[tid] = (cx + w * 0.5f) * IMG_SZ;
        y2[tid] = (cy + h * 0.5f) * IMG_SZ;
        lab[tid] = c;
    }
    __syncthreads();

    float mx = -INFINITY;
    if (tid < NCAND) mx = fmaxf(fmaxf(x1[tid], y1[tid]), fmaxf(x2[tid], y2[tid]));
#pragma unroll
    for (int off = 32; off >= 1; off >>= 1) mx = fmaxf(mx, __shfl_xor(mx, off));
    if (lane == 0) wred[wv] = mx;
    __syncthreads();
    if (tid == 0) {
        float mm = -INFINITY;
        for (int t = 0; t < 16; ++t) mm = fmaxf(mm, wred[t]);
        maxc_sh = mm;
    }
    __syncthreads();

    if (tid < NPAD) {
        if (tid < NCAND) {
            float off = (float)lab[tid] * (maxc_sh + 1.0f);
            ox1[tid] = x1[tid] + off;
            oy1[tid] = y1[tid] + off;
            ox2[tid] = x2[tid] + off;
            oy2[tid] = y2[tid] + off;
            areas[tid] = (ox2[tid] - ox1[tid]) * (oy2[tid] - oy1[tid]);
        } else {
            ox1[tid] = 1e30f; oy1[tid] = 1e30f;
            ox2[tid] = 1e30f; oy2[tid] = 1e30f;
            areas[tid] = 0.0f;
        }
    }
    __syncthreads();

    // IoU masks via ballot (16 waves)
    for (int i = wv; i < NCAND; i += 16) {
        float a1 = ox1[i], b1 = oy1[i], a2 = ox2[i], b2 = oy2[i], ar = areas[i];
#pragma unroll
        for (int wd = 0; wd < NWORDS; ++wd) {
            int j = wd * 64 + lane;
            float iw_ = fmaxf(fminf(a2, ox2[j]) - fmaxf(a1, ox1[j]), 0.0f);
            float ih_ = fmaxf(fminf(b2, oy2[j]) - fmaxf(b1, oy1[j]), 0.0f);
            float inter = iw_ * ih_;
            float uni = ar + areas[j] - inter;
            float iou = inter / fmaxf(uni, 1e-12f);
            unsigned long long bits = __ballot(iou > NMS_THR);
            if (lane == 0) M[i][wd] = bits;
        }
    }
    __syncthreads();

    // greedy NMS: wave 0, M rows pre-distributed across lanes, readlane core.
    // Only accumulate suppression into current/future words (past words dead).
    if (wv == 0) {
        unsigned long long acc[NWORDS] = {0, 0, 0, 0, 0, 0, 0};
        unsigned long long keepw[NWORDS];
#pragma unroll
        for (int iw = 0; iw < NWORDS; ++iw) {
            unsigned long long mrow[NWORDS];
#pragma unroll
            for (int w = iw; w < NWORDS; ++w) mrow[w] = M[iw * 64 + lane][w];
            unsigned long long sup = acc[iw];
            unsigned long long K = 0;
            int nb = (iw == NWORDS - 1) ? (NCAND - 64 * (NWORDS - 1)) : 64;
            for (int ib = 0; ib < nb; ++ib) {
                if (!((sup >> ib) & 1ull)) {
                    K |= (1ull << ib);
                    int lo, hi;
                    lo = __builtin_amdgcn_readlane((int)(unsigned)mrow[iw], ib);
                    hi = __builtin_amdgcn_readlane((int)(unsigned)(mrow[iw] >> 32), ib);
                    sup |= ((unsigned long long)(unsigned)hi << 32) | (unsigned)lo;
#pragma unroll
                    for (int w = iw + 1; w < NWORDS; ++w) {
                        lo = __builtin_amdgcn_readlane((int)(unsigned)mrow[w], ib);
                        hi = __builtin_amdgcn_readlane((int)(unsigned)(mrow[w] >> 32), ib);
                        acc[w] |= ((unsigned long long)(unsigned)hi << 32) | (unsigned)lo;
                    }
                }
            }
            keepw[iw] = K;
        }
        if (lane == 0) {
            int a = 0;
#pragma unroll
            for (int w = 0; w < NWORDS; ++w) {
                keepw_s[w] = keepw[w];
                wpre_s[w] = a;
                a += __popcll(keepw[w]);
            }
            wpre_s[NWORDS] = a;
        }
    }
    __syncthreads();

    // kidx: kept (ascending) then unkept (ascending)
    if (tid < NCAND) {
        int w = tid >> 6, bb = tid & 63;
        unsigned long long kwv = keepw_s[w];
        bool kp = (kwv >> bb) & 1ull;
        unsigned long long below_mask = (bb == 0) ? 0ull : (~0ull >> (64 - bb));
        int below = wpre_s[w] + __popcll(kwv & below_mask);
        int nkept = wpre_s[NWORDS];
        int pos = kp ? below : nkept + (tid - below);
        if (pos < NOUT) kidx[pos] = tid;
    }
    __syncthreads();

    if (tid < NOUT) {
        int i = kidx[tid];
        bool kp = (keepw_s[i >> 6] >> (i & 63)) & 1ull;
        float* ob = out + ((size_t)img * NOUT + tid) * 4;
        ob[0] = x1[i];
        ob[1] = y1[i];
        ob[2] = x2[i];
        ob[3] = y2[i];
        out[(size_t)BATCH * NOUT * 4 + (size_t)img * NOUT + tid] = (float)lab[i];
        out[(size_t)BATCH * NOUT * 4 + (size_t)BATCH * NOUT + (size_t)img * NOUT + tid] =
            kp ? scs[i] : -INFINITY;
    }
}

extern "C" void kernel_launch(void* const* d_in, const int* in_sizes, int n_in,
                              void* d_out, int out_size, void* d_ws, size_t ws_size,
                              hipStream_t stream) {
    const float* logits = (const float*)d_in[0];
    const float* bbox = (const float*)d_in[1];
    const float* priors = (const float*)d_in[2];
    float* out = (float*)d_out;
    char* ws = (char*)d_ws;

    unsigned* hist = (unsigned*)(ws + OFF_HIST);
    unsigned* gcnt = (unsigned*)(ws + OFF_GCNT);
    unsigned long long* cand = (unsigned long long*)(ws + OFF_CAND);

    hipMemsetAsync(ws, 0, OFF_CAND, stream);  // zero hist + gcnt

    dim3 g1(P / RPB, BATCH);
    k_hist<<<g1, 256, 0, stream>>>(logits, hist, gcnt, cand);
    k_post<<<BATCH, 1024, 0, stream>>>(bbox, priors, hist, gcnt, cand, out);
}

// Round 3
// 382.884 us; speedup vs baseline: 1.0261x; 1.0261x over previous
//
#include <hip/hip_runtime.h>
#include <math.h>

#define BATCH 16
#define P 32768
#define C 81
#define CM1 80
#define NCAND 400
#define NOUT 100
#define NBINS 256
#define SMIN_F (-3.0f)
#define BIN_SCALE (NBINS / 3.0f)
#define SORTN 1024
#define IMG_SZ 512.0f
#define NMS_THR 0.45f
#define NWORDS 7
#define NPAD 448
#define RPB 64        // rows per block in the streaming pass
#define LCAP 448      // per-block candidate staging (mean ~150, ~8.5 sigma headroom)
#define CAND_CAP 131072  // per-image global candidate cap (expected ~76K)

// ---- workspace layout (bytes) ----
#define OFF_HIST 0                               // BATCH*NBINS*4 = 16384
#define OFF_GCNT 16384                           // BATCH*4 = 64
#define OFF_CAND 16448                           // BATCH*CAND_CAP*8 = 16 MB
#define NEED_WS (OFF_CAND + (size_t)BATCH * CAND_CAP * 8)

__device__ __forceinline__ int score_bin(float sc) {
    int b = (int)((sc - SMIN_F) * BIN_SCALE);
    return b < 0 ? 0 : (b > NBINS - 1 ? NBINS - 1 : b);
}

// Quad-per-row stats: lane q of a 4-lane quad holds columns c = 4k+q,
// reductions via xor-1/xor-2. Single site (scores computed once, in k_hist).
// m/l op order must stay fixed: output scores are bit-matched to the JAX ref.
__device__ __forceinline__ void quad_stats(const float* __restrict__ rowp, int q,
                                           float r[21], float& m, float& l) {
#pragma unroll
    for (int k = 0; k < 21; ++k) {
        int c = 4 * k + q;
        r[k] = (c < C) ? rowp[c] : -INFINITY;
    }
    float mm = -INFINITY;
#pragma unroll
    for (int k = 0; k < 21; ++k) mm = fmaxf(mm, r[k]);
    mm = fmaxf(mm, __shfl_xor(mm, 1));
    mm = fmaxf(mm, __shfl_xor(mm, 2));
    float s = 0.0f;
#pragma unroll
    for (int k = 0; k < 21; ++k) {
        int c = 4 * k + q;
        if (c < C) s += __expf(r[k] - mm);
    }
    s += __shfl_xor(s, 1);
    s += __shfl_xor(s, 2);
    m = mm;
    l = __logf(s);
}

// Monotone-decreasing-in-value, unique (id in low bits) sort key.
// pack/unpack is an exact involution on the float bits.
__device__ __forceinline__ unsigned long long pack_key(float v, unsigned id) {
    unsigned bits = __float_as_uint(v);
    unsigned u = (bits & 0x80000000u) ? ~bits : (bits | 0x80000000u);
    return ((unsigned long long)(~u) << 32) | id;  // asc key == desc value, asc idx
}

__device__ __forceinline__ float unpack_score(unsigned long long kk) {
    unsigned uu = ~(unsigned)(kk >> 32);
    unsigned bits = (uu & 0x80000000u) ? (uu & 0x7FFFFFFFu) : ~uu;
    return __uint_as_float(bits);
}

// ---- pass 1: linear float4 staging into LDS, quad-per-row stats,
// histogram of scores > SMIN_F + direct candidate-list emission.
// LDS = 20736 (tile) + 1024 (lh) + 3584 (lc) + 8 = 25352 B -> 6 blocks/CU.
__global__ __launch_bounds__(256) void k_hist(const float* __restrict__ logits,
                                              unsigned* __restrict__ hist,
                                              unsigned* __restrict__ gcnt,
                                              unsigned long long* __restrict__ cand) {
    __shared__ float tile[RPB * C];          // 20736 B
    __shared__ unsigned lh[NBINS];           // 1 KB
    __shared__ unsigned long long lc[LCAP];  // 3.5 KB
    __shared__ int lcnt_sh;
    __shared__ int base_sh;
    int img = blockIdx.y;
    int row0 = blockIdx.x * RPB;
    lh[threadIdx.x] = 0;
    if (threadIdx.x == 0) lcnt_sh = 0;
    const float4* g4 = (const float4*)(logits + ((size_t)img * P + row0) * C);
    float4* t4 = (float4*)tile;
#pragma unroll
    for (int i = 0; i < 6; ++i) {
        int idx = threadIdx.x + i * 256;
        if (idx < RPB * C / 4) t4[idx] = g4[idx];
    }
    __syncthreads();
    int quad = threadIdx.x >> 2, q = threadIdx.x & 3;
    const float* rowp = tile + quad * C;
    float r[21], m, l;
    quad_stats(rowp, q, r, m, l);
    int row = row0 + quad;
#pragma unroll
    for (int k = 0; k < 21; ++k) {
        int c = 4 * k + q;
        if (c >= 1 && c < C) {
            float sc = (r[k] - m) - l;
            if (sc > SMIN_F) {
                atomicAdd(&lh[score_bin(sc)], 1u);
                int pos = atomicAdd(&lcnt_sh, 1);
                if (pos < LCAP) lc[pos] = pack_key(sc, (unsigned)(row * CM1 + c - 1));
            }
        }
    }
    __syncthreads();
    unsigned h = lh[threadIdx.x];
    if (h) atomicAdd(&hist[(size_t)img * NBINS + threadIdx.x], h);
    int n = lcnt_sh;
    if (n > LCAP) n = LCAP;
    if (threadIdx.x == 0) base_sh = (int)atomicAdd(&gcnt[img], (unsigned)n);
    __syncthreads();
    int base = base_sh;
    unsigned long long* dst = cand + (size_t)img * CAND_CAP;
    for (int i = threadIdx.x; i < n; i += 256) {
        int pos = base + i;
        if (pos < CAND_CAP) dst[pos] = lc[i];
    }
}

// ---- pass 2: one block per image, 1024 threads (16 waves).
// threshold -> filter candidate list -> register bitonic sort -> decode ->
// IoU -> greedy NMS -> outputs.
__global__ __launch_bounds__(1024) void k_post(const float* __restrict__ bbox,
                                               const float* __restrict__ priors,
                                               const unsigned* __restrict__ hist,
                                               const unsigned* __restrict__ gcnt,
                                               const unsigned long long* __restrict__ cand,
                                               float* __restrict__ out) {
    __shared__ int tb_sh, ncand_sh;
    __shared__ unsigned long long key[SORTN];
    __shared__ float x1[NCAND], y1[NCAND], x2[NCAND], y2[NCAND];
    __shared__ float ox1[NPAD], oy1[NPAD], ox2[NPAD], oy2[NPAD], areas[NPAD];
    __shared__ float scs[NCAND];
    __shared__ int lab[NCAND];
    __shared__ unsigned long long M[NPAD][NWORDS];
    __shared__ unsigned long long keepw_s[NWORDS];
    __shared__ int wpre_s[NWORDS + 1];
    __shared__ float wred[16];
    __shared__ float maxc_sh;
    __shared__ int kidx[NOUT];

    int img = blockIdx.x;
    int tid = threadIdx.x;
    int lane = tid & 63;
    int wv = tid >> 6;

    if (tid == 0) { tb_sh = 0; ncand_sh = 0; }
    key[tid] = pack_key(-INFINITY, 0x7FFFFFFFu);

    // wave 0: histogram suffix-scan -> threshold bin (exact unsigned sums).
    if (wv == 0) {
        uint4 h4 = ((const uint4*)(hist + (size_t)img * NBINS))[lane];
        unsigned own = h4.x + h4.y + h4.z + h4.w;
        unsigned acc = own;
#pragma unroll
        for (int off = 1; off < 64; off <<= 1) {
            unsigned t = __shfl_down(acc, off);
            if (lane + off < 64) acc += t;
        }
        unsigned above = acc - own;        // sum of bins >= 4*(lane+1)
        unsigned s3 = above + h4.w;        // suffix(4*lane+3)
        unsigned s2 = s3 + h4.z;
        unsigned s1 = s2 + h4.y;
        unsigned s0 = s1 + h4.x;           // suffix(4*lane)
        int best = -1;
        if (s0 >= NCAND) best = 4 * lane + 0;
        if (s1 >= NCAND) best = 4 * lane + 1;
        if (s2 >= NCAND) best = 4 * lane + 2;
        if (s3 >= NCAND) best = 4 * lane + 3;
#pragma unroll
        for (int off = 32; off >= 1; off >>= 1) {
            int o = __shfl_xor(best, off);
            best = best > o ? best : o;
        }
        if (lane == 0) tb_sh = best < 0 ? 0 : best;
    }
    __syncthreads();
    int tb = tb_sh;

    // stream the per-image candidate list (vectorized, 2-deep unrolled);
    // keep bin >= tb. Same filter set as before; unique keys + full sort
    // make append order irrelevant.
    {
        int n = (int)gcnt[img];
        if (n > CAND_CAP) n = CAND_CAP;
        const ulonglong2* src2 = (const ulonglong2*)(cand + (size_t)img * CAND_CAP);
        int npair = n >> 1;
        for (int base = 0; base < npair; base += 2048) {
            int i0 = base + tid, i1 = base + 1024 + tid;
            ulonglong2 a, b;
            bool va = i0 < npair, vb = i1 < npair;
            if (va) a = src2[i0];
            if (vb) b = src2[i1];
            if (va) {
                if (score_bin(unpack_score(a.x)) >= tb) {
                    int pos = atomicAdd(&ncand_sh, 1);
                    if (pos < SORTN) key[pos] = a.x;
                }
                if (score_bin(unpack_score(a.y)) >= tb) {
                    int pos = atomicAdd(&ncand_sh, 1);
                    if (pos < SORTN) key[pos] = a.y;
                }
            }
            if (vb) {
                if (score_bin(unpack_score(b.x)) >= tb) {
                    int pos = atomicAdd(&ncand_sh, 1);
                    if (pos < SORTN) key[pos] = b.x;
                }
                if (score_bin(unpack_score(b.y)) >= tb) {
                    int pos = atomicAdd(&ncand_sh, 1);
                    if (pos < SORTN) key[pos] = b.y;
                }
            }
        }
        if ((n & 1) && tid == 0) {
            unsigned long long kk = ((const unsigned long long*)src2)[n - 1];
            if (score_bin(unpack_score(kk)) >= tb) {
                int pos = atomicAdd(&ncand_sh, 1);
                if (pos < SORTN) key[pos] = kk;
            }
        }
    }
    __syncthreads();

    // register-resident bitonic sort, ascending on u64 keys.
    // thread t owns element t. j<=32 phases are intra-wave (shfl_xor, no
    // barrier) - 45 of 55 phases. Only j>=64 phases exchange through LDS.
    unsigned long long kr = key[tid];
#pragma unroll
    for (int k2 = 2; k2 <= 64; k2 <<= 1) {
        for (int j = k2 >> 1; j > 0; j >>= 1) {
            unsigned long long pv = __shfl_xor(kr, j);
            bool takeMin = (((tid & j) == 0) == ((tid & k2) == 0));
            bool sel = takeMin ? (pv < kr) : (pv > kr);
            if (sel) kr = pv;
        }
    }
    for (int k2 = 128; k2 <= SORTN; k2 <<= 1) {
        for (int j = k2 >> 1; j >= 64; j >>= 1) {
            __syncthreads();   // prior phase's reads done before overwrite
            key[tid] = kr;
            __syncthreads();
            unsigned long long pv = key[tid ^ j];
            bool takeMin = (((tid & j) == 0) == ((tid & k2) == 0));
            bool sel = takeMin ? (pv < kr) : (pv > kr);
            if (sel) kr = pv;
        }
#pragma unroll
        for (int j = 32; j > 0; j >>= 1) {
            unsigned long long pv = __shfl_xor(kr, j);
            bool takeMin = (((tid & j) == 0) == ((tid & k2) == 0));
            bool sel = takeMin ? (pv < kr) : (pv > kr);
            if (sel) kr = pv;
        }
    }

    // decode top-400 (element tid lives in thread tid's register)
    if (tid < NCAND) {
        scs[tid] = unpack_score(kr);
        unsigned f = (unsigned)(kr & 0xFFFFFFFFu);
        if (f > (unsigned)(P * CM1 - 1)) f = (unsigned)(P * CM1 - 1);
        int p = (int)(f / CM1);
        int c = (int)(f % CM1) + 1;
        const float* lp = bbox + ((size_t)img * P + p) * 4;
        const float* pp = priors + (size_t)p * 4;
        float cx = lp[0] * 0.1f * pp[2] + pp[0];
        float cy = lp[1] * 0.1f * pp[3] + pp[1];
        float w = expf(lp[2] * 0.2f) * pp[2];
        float h = expf(lp[3] * 0.2f) * pp[3];
        x1[tid] = (cx - w * 0.5f) * IMG_SZ;
        y1[tid] = (cy - h * 0.5f) * IMG_SZ;
        x2[tid] = (cx + w * 0.5f) * IMG_SZ;
        y2[tid] = (cy + h * 0.5f) * IMG_SZ;
        lab[tid] = c;
    }
    __syncthreads();

    float mx = -INFINITY;
    if (tid < NCAND) mx = fmaxf(fmaxf(x1[tid], y1[tid]), fmaxf(x2[tid], y2[tid]));
#pragma unroll
    for (int off = 32; off >= 1; off >>= 1) mx = fmaxf(mx, __shfl_xor(mx, off));
    if (lane == 0) wred[wv] = mx;
    __syncthreads();
    if (tid == 0) {
        float mm = -INFINITY;
        for (int t = 0; t < 16; ++t) mm = fmaxf(mm, wred[t]);
        maxc_sh = mm;
    }
    __syncthreads();

    if (tid < NPAD) {
        if (tid < NCAND) {
            float off = (float)lab[tid] * (maxc_sh + 1.0f);
            ox1[tid] = x1[tid] + off;
            oy1[tid] = y1[tid] + off;
            ox2[tid] = x2[tid] + off;
            oy2[tid] = y2[tid] + off;
            areas[tid] = (ox2[tid] - ox1[tid]) * (oy2[tid] - oy1[tid]);
        } else {
            ox1[tid] = 1e30f; oy1[tid] = 1e30f;
            ox2[tid] = 1e30f; oy2[tid] = 1e30f;
            areas[tid] = 0.0f;
        }
    }
    __syncthreads();

    // IoU masks via ballot (16 waves)
    for (int i = wv; i < NCAND; i += 16) {
        float a1 = ox1[i], b1 = oy1[i], a2 = ox2[i], b2 = oy2[i], ar = areas[i];
#pragma unroll
        for (int wd = 0; wd < NWORDS; ++wd) {
            int j = wd * 64 + lane;
            float iw_ = fmaxf(fminf(a2, ox2[j]) - fmaxf(a1, ox1[j]), 0.0f);
            float ih_ = fmaxf(fminf(b2, oy2[j]) - fmaxf(b1, oy1[j]), 0.0f);
            float inter = iw_ * ih_;
            float uni = ar + areas[j] - inter;
            float iou = inter / fmaxf(uni, 1e-12f);
            unsigned long long bits = __ballot(iou > NMS_THR);
            if (lane == 0) M[i][wd] = bits;
        }
    }
    __syncthreads();

    // greedy NMS: wave 0, M rows pre-distributed across lanes, readlane core.
    // Only accumulate suppression into current/future words (past words dead).
    if (wv == 0) {
        unsigned long long acc[NWORDS] = {0, 0, 0, 0, 0, 0, 0};
        unsigned long long keepw[NWORDS];
#pragma unroll
        for (int iw = 0; iw < NWORDS; ++iw) {
            unsigned long long mrow[NWORDS];
#pragma unroll
            for (int w = iw; w < NWORDS; ++w) mrow[w] = M[iw * 64 + lane][w];
            unsigned long long sup = acc[iw];
            unsigned long long K = 0;
            int nb = (iw == NWORDS - 1) ? (NCAND - 64 * (NWORDS - 1)) : 64;
            for (int ib = 0; ib < nb; ++ib) {
                if (!((sup >> ib) & 1ull)) {
                    K |= (1ull << ib);
                    int lo, hi;
                    lo = __builtin_amdgcn_readlane((int)(unsigned)mrow[iw], ib);
                    hi = __builtin_amdgcn_readlane((int)(unsigned)(mrow[iw] >> 32), ib);
                    sup |= ((unsigned long long)(unsigned)hi << 32) | (unsigned)lo;
#pragma unroll
                    for (int w = iw + 1; w < NWORDS; ++w) {
                        lo = __builtin_amdgcn_readlane((int)(unsigned)mrow[w], ib);
                        hi = __builtin_amdgcn_readlane((int)(unsigned)(mrow[w] >> 32), ib);
                        acc[w] |= ((unsigned long long)(unsigned)hi << 32) | (unsigned)lo;
                    }
                }
            }
            keepw[iw] = K;
        }
        if (lane == 0) {
            int a = 0;
#pragma unroll
            for (int w = 0; w < NWORDS; ++w) {
                keepw_s[w] = keepw[w];
                wpre_s[w] = a;
                a += __popcll(keepw[w]);
            }
            wpre_s[NWORDS] = a;
        }
    }
    __syncthreads();

    // kidx: kept (ascending) then unkept (ascending)
    if (tid < NCAND) {
        int w = tid >> 6, bb = tid & 63;
        unsigned long long kwv = keepw_s[w];
        bool kp = (kwv >> bb) & 1ull;
        unsigned long long below_mask = (bb == 0) ? 0ull : (~0ull >> (64 - bb));
        int below = wpre_s[w] + __popcll(kwv & below_mask);
        int nkept = wpre_s[NWORDS];
        int pos = kp ? below : nkept + (tid - below);
        if (pos < NOUT) kidx[pos] = tid;
    }
    __syncthreads();

    if (tid < NOUT) {
        int i = kidx[tid];
        bool kp = (keepw_s[i >> 6] >> (i & 63)) & 1ull;
        float* ob = out + ((size_t)img * NOUT + tid) * 4;
        ob[0] = x1[i];
        ob[1] = y1[i];
        ob[2] = x2[i];
        ob[3] = y2[i];
        out[(size_t)BATCH * NOUT * 4 + (size_t)img * NOUT + tid] = (float)lab[i];
        out[(size_t)BATCH * NOUT * 4 + (size_t)BATCH * NOUT + (size_t)img * NOUT + tid] =
            kp ? scs[i] : -INFINITY;
    }
}

extern "C" void kernel_launch(void* const* d_in, const int* in_sizes, int n_in,
                              void* d_out, int out_size, void* d_ws, size_t ws_size,
                              hipStream_t stream) {
    const float* logits = (const float*)d_in[0];
    const float* bbox = (const float*)d_in[1];
    const float* priors = (const float*)d_in[2];
    float* out = (float*)d_out;
    char* ws = (char*)d_ws;

    unsigned* hist = (unsigned*)(ws + OFF_HIST);
    unsigned* gcnt = (unsigned*)(ws + OFF_GCNT);
    unsigned long long* cand = (unsigned long long*)(ws + OFF_CAND);

    hipMemsetAsync(ws, 0, OFF_CAND, stream);  // zero hist + gcnt

    dim3 g1(P / RPB, BATCH);
    k_hist<<<g1, 256, 0, stream>>>(logits, hist, gcnt, cand);
    k_post<<<BATCH, 1024, 0, stream>>>(bbox, priors, hist, gcnt, cand, out);
}

// Round 4
// 381.132 us; speedup vs baseline: 1.0309x; 1.0046x over previous
//
#include <hip/hip_runtime.h>
#include <math.h>

#define BATCH 16
#define P 32768
#define C 81
#define CM1 80
#define NCAND 400
#define NOUT 100
#define NBINS 256
#define SMIN_F (-3.0f)
#define BIN_SCALE (NBINS / 3.0f)
#define SORTN 1024
#define IMG_SZ 512.0f
#define NMS_THR 0.45f
#define NWORDS 7
#define NPAD 448
#define RPB 64        // rows per block in the streaming pass
#define NBLK (P / RPB)  // 512 k_hist blocks per image
#define LCAP 448      // per-block candidate segment (mean ~150, ~8 sigma headroom)

// ---- workspace layout (bytes) ----
#define OFF_HIST 0                               // BATCH*NBINS*4 = 16384
#define OFF_CNT 16384                            // BATCH*NBLK*4 = 32768
#define OFF_CAND 49152                           // BATCH*NBLK*LCAP*8 = 28 MB
#define NEED_WS (OFF_CAND + (size_t)BATCH * NBLK * LCAP * 8)

__device__ __forceinline__ int score_bin(float sc) {
    int b = (int)((sc - SMIN_F) * BIN_SCALE);
    return b < 0 ? 0 : (b > NBINS - 1 ? NBINS - 1 : b);
}

// Quad-per-row stats: lane q of a 4-lane quad holds columns c = 4k+q,
// reductions via xor-1/xor-2. Single site (scores computed once, in k_hist).
// m/l op order must stay fixed: output scores are bit-matched to the JAX ref.
__device__ __forceinline__ void quad_stats(const float* __restrict__ rowp, int q,
                                           float r[21], float& m, float& l) {
#pragma unroll
    for (int k = 0; k < 21; ++k) {
        int c = 4 * k + q;
        r[k] = (c < C) ? rowp[c] : -INFINITY;
    }
    float mm = -INFINITY;
#pragma unroll
    for (int k = 0; k < 21; ++k) mm = fmaxf(mm, r[k]);
    mm = fmaxf(mm, __shfl_xor(mm, 1));
    mm = fmaxf(mm, __shfl_xor(mm, 2));
    float s = 0.0f;
#pragma unroll
    for (int k = 0; k < 21; ++k) {
        int c = 4 * k + q;
        if (c < C) s += __expf(r[k] - mm);
    }
    s += __shfl_xor(s, 1);
    s += __shfl_xor(s, 2);
    m = mm;
    l = __logf(s);
}

// Monotone-decreasing-in-value, unique (id in low bits) sort key.
// pack/unpack is an exact involution on the float bits.
__device__ __forceinline__ unsigned long long pack_key(float v, unsigned id) {
    unsigned bits = __float_as_uint(v);
    unsigned u = (bits & 0x80000000u) ? ~bits : (bits | 0x80000000u);
    return ((unsigned long long)(~u) << 32) | id;  // asc key == desc value, asc idx
}

__device__ __forceinline__ float unpack_score(unsigned long long kk) {
    unsigned uu = ~(unsigned)(kk >> 32);
    unsigned bits = (uu & 0x80000000u) ? (uu & 0x7FFFFFFFu) : ~uu;
    return __uint_as_float(bits);
}

// ---- pass 1: linear float4 staging into LDS, quad-per-row stats,
// histogram of scores > SMIN_F + candidate emission into a PRIVATE per-block
// segment (no value-returning global atomic -> no block-wide stall chain).
__global__ __launch_bounds__(256) void k_hist(const float* __restrict__ logits,
                                              unsigned* __restrict__ hist,
                                              unsigned* __restrict__ cnt,
                                              unsigned long long* __restrict__ cand) {
    __shared__ float tile[RPB * C];          // 20736 B
    __shared__ unsigned lh[NBINS];           // 1 KB
    __shared__ unsigned long long lc[LCAP];  // 3.5 KB
    __shared__ int lcnt_sh;
    int img = blockIdx.y;
    int row0 = blockIdx.x * RPB;
    lh[threadIdx.x] = 0;
    if (threadIdx.x == 0) lcnt_sh = 0;
    const float4* g4 = (const float4*)(logits + ((size_t)img * P + row0) * C);
    float4* t4 = (float4*)tile;
#pragma unroll
    for (int i = 0; i < 6; ++i) {
        int idx = threadIdx.x + i * 256;
        if (idx < RPB * C / 4) t4[idx] = g4[idx];
    }
    __syncthreads();
    int quad = threadIdx.x >> 2, q = threadIdx.x & 3;
    const float* rowp = tile + quad * C;
    float r[21], m, l;
    quad_stats(rowp, q, r, m, l);
    int row = row0 + quad;
#pragma unroll
    for (int k = 0; k < 21; ++k) {
        int c = 4 * k + q;
        if (c >= 1 && c < C) {
            float sc = (r[k] - m) - l;
            if (sc > SMIN_F) {
                atomicAdd(&lh[score_bin(sc)], 1u);
                int pos = atomicAdd(&lcnt_sh, 1);
                if (pos < LCAP) lc[pos] = pack_key(sc, (unsigned)(row * CM1 + c - 1));
            }
        }
    }
    __syncthreads();
    unsigned h = lh[threadIdx.x];
    if (h) atomicAdd(&hist[(size_t)img * NBINS + threadIdx.x], h);
    int n = lcnt_sh;
    if (n > LCAP) n = LCAP;
    unsigned long long* dst = cand + ((size_t)img * NBLK + blockIdx.x) * LCAP;
    for (int i = threadIdx.x; i < n; i += 256) dst[i] = lc[i];
    if (threadIdx.x == 0) cnt[(size_t)img * NBLK + blockIdx.x] = (unsigned)n;
}

// ---- pass 2: one block per image, 1024 threads (16 waves).
// threshold -> segment-walk filter -> register bitonic sort -> decode ->
// IoU -> greedy NMS -> outputs.
__global__ __launch_bounds__(1024) void k_post(const float* __restrict__ bbox,
                                               const float* __restrict__ priors,
                                               const unsigned* __restrict__ hist,
                                               const unsigned* __restrict__ cnt,
                                               const unsigned long long* __restrict__ cand,
                                               float* __restrict__ out) {
    __shared__ int tb_sh, ncand_sh;
    __shared__ unsigned scnt[NBLK];          // 2 KB: per-segment counts
    __shared__ unsigned long long key[SORTN];
    __shared__ float x1[NCAND], y1[NCAND], x2[NCAND], y2[NCAND];
    __shared__ float ox1[NPAD], oy1[NPAD], ox2[NPAD], oy2[NPAD], areas[NPAD];
    __shared__ float scs[NCAND];
    __shared__ int lab[NCAND];
    __shared__ unsigned long long M[NPAD][NWORDS];
    __shared__ unsigned long long keepw_s[NWORDS];
    __shared__ int wpre_s[NWORDS + 1];
    __shared__ float wred[16];
    __shared__ float maxc_sh;
    __shared__ int kidx[NOUT];

    int img = blockIdx.x;
    int tid = threadIdx.x;
    int lane = tid & 63;
    int wv = tid >> 6;

    if (tid == 0) { tb_sh = 0; ncand_sh = 0; }
    key[tid] = pack_key(-INFINITY, 0x7FFFFFFFu);
    if (tid < NBLK) scnt[tid] = cnt[(size_t)img * NBLK + tid];

    // wave 0: histogram suffix-scan -> threshold bin (exact unsigned sums).
    if (wv == 0) {
        uint4 h4 = ((const uint4*)(hist + (size_t)img * NBINS))[lane];
        unsigned own = h4.x + h4.y + h4.z + h4.w;
        unsigned acc = own;
#pragma unroll
        for (int off = 1; off < 64; off <<= 1) {
            unsigned t = __shfl_down(acc, off);
            if (lane + off < 64) acc += t;
        }
        unsigned above = acc - own;        // sum of bins >= 4*(lane+1)
        unsigned s3 = above + h4.w;        // suffix(4*lane+3)
        unsigned s2 = s3 + h4.z;
        unsigned s1 = s2 + h4.y;
        unsigned s0 = s1 + h4.x;           // suffix(4*lane)
        int best = -1;
        if (s0 >= NCAND) best = 4 * lane + 0;
        if (s1 >= NCAND) best = 4 * lane + 1;
        if (s2 >= NCAND) best = 4 * lane + 2;
        if (s3 >= NCAND) best = 4 * lane + 3;
#pragma unroll
        for (int off = 32; off >= 1; off >>= 1) {
            int o = __shfl_xor(best, off);
            best = best > o ? best : o;
        }
        if (lane == 0) tb_sh = best < 0 ? 0 : best;
    }
    __syncthreads();
    int tb = tb_sh;

    // segment-walk filter: wave wv handles segments wv, wv+16, ...
    // Each segment's entries are contiguous u64s (coalesced 64-lane reads).
    // Same candidate set as before; unique keys + full sort make append
    // order irrelevant.
    {
        const unsigned long long* base = cand + (size_t)img * NBLK * LCAP;
        for (int s = wv; s < NBLK; s += 16) {
            int n = (int)scnt[s];
            const unsigned long long* seg = base + (size_t)s * LCAP;
            for (int i = lane; i < n; i += 64) {
                unsigned long long kk = seg[i];
                if (score_bin(unpack_score(kk)) >= tb) {
                    int pos = atomicAdd(&ncand_sh, 1);
                    if (pos < SORTN) key[pos] = kk;
                }
            }
        }
    }
    __syncthreads();

    // register-resident bitonic sort, ascending on u64 keys.
    // thread t owns element t. j<=32 phases are intra-wave (shfl_xor, no
    // barrier) - 45 of 55 phases. Only j>=64 phases exchange through LDS.
    unsigned long long kr = key[tid];
#pragma unroll
    for (int k2 = 2; k2 <= 64; k2 <<= 1) {
        for (int j = k2 >> 1; j > 0; j >>= 1) {
            unsigned long long pv = __shfl_xor(kr, j);
            bool takeMin = (((tid & j) == 0) == ((tid & k2) == 0));
            bool sel = takeMin ? (pv < kr) : (pv > kr);
            if (sel) kr = pv;
        }
    }
    for (int k2 = 128; k2 <= SORTN; k2 <<= 1) {
        for (int j = k2 >> 1; j >= 64; j >>= 1) {
            __syncthreads();   // prior phase's reads done before overwrite
            key[tid] = kr;
            __syncthreads();
            unsigned long long pv = key[tid ^ j];
            bool takeMin = (((tid & j) == 0) == ((tid & k2) == 0));
            bool sel = takeMin ? (pv < kr) : (pv > kr);
            if (sel) kr = pv;
        }
#pragma unroll
        for (int j = 32; j > 0; j >>= 1) {
            unsigned long long pv = __shfl_xor(kr, j);
            bool takeMin = (((tid & j) == 0) == ((tid & k2) == 0));
            bool sel = takeMin ? (pv < kr) : (pv > kr);
            if (sel) kr = pv;
        }
    }

    // decode top-400 (element tid lives in thread tid's register)
    if (tid < NCAND) {
        scs[tid] = unpack_score(kr);
        unsigned f = (unsigned)(kr & 0xFFFFFFFFu);
        if (f > (unsigned)(P * CM1 - 1)) f = (unsigned)(P * CM1 - 1);
        int p = (int)(f / CM1);
        int c = (int)(f % CM1) + 1;
        const float* lp = bbox + ((size_t)img * P + p) * 4;
        const float* pp = priors + (size_t)p * 4;
        float cx = lp[0] * 0.1f * pp[2] + pp[0];
        float cy = lp[1] * 0.1f * pp[3] + pp[1];
        float w = expf(lp[2] * 0.2f) * pp[2];
        float h = expf(lp[3] * 0.2f) * pp[3];
        x1[tid] = (cx - w * 0.5f) * IMG_SZ;
        y1[tid] = (cy - h * 0.5f) * IMG_SZ;
        x2[tid] = (cx + w * 0.5f) * IMG_SZ;
        y2[tid] = (cy + h * 0.5f) * IMG_SZ;
        lab[tid] = c;
    }
    __syncthreads();

    float mx = -INFINITY;
    if (tid < NCAND) mx = fmaxf(fmaxf(x1[tid], y1[tid]), fmaxf(x2[tid], y2[tid]));
#pragma unroll
    for (int off = 32; off >= 1; off >>= 1) mx = fmaxf(mx, __shfl_xor(mx, off));
    if (lane == 0) wred[wv] = mx;
    __syncthreads();
    if (tid == 0) {
        float mm = -INFINITY;
        for (int t = 0; t < 16; ++t) mm = fmaxf(mm, wred[t]);
        maxc_sh = mm;
    }
    __syncthreads();

    if (tid < NPAD) {
        if (tid < NCAND) {
            float off = (float)lab[tid] * (maxc_sh + 1.0f);
            ox1[tid] = x1[tid] + off;
            oy1[tid] = y1[tid] + off;
            ox2[tid] = x2[tid] + off;
            oy2[tid] = y2[tid] + off;
            areas[tid] = (ox2[tid] - ox1[tid]) * (oy2[tid] - oy1[tid]);
        } else {
            ox1[tid] = 1e30f; oy1[tid] = 1e30f;
            ox2[tid] = 1e30f; oy2[tid] = 1e30f;
            areas[tid] = 0.0f;
        }
    }
    __syncthreads();

    // IoU masks via ballot (16 waves)
    for (int i = wv; i < NCAND; i += 16) {
        float a1 = ox1[i], b1 = oy1[i], a2 = ox2[i], b2 = oy2[i], ar = areas[i];
#pragma unroll
        for (int wd = 0; wd < NWORDS; ++wd) {
            int j = wd * 64 + lane;
            float iw_ = fmaxf(fminf(a2, ox2[j]) - fmaxf(a1, ox1[j]), 0.0f);
            float ih_ = fmaxf(fminf(b2, oy2[j]) - fmaxf(b1, oy1[j]), 0.0f);
            float inter = iw_ * ih_;
            float uni = ar + areas[j] - inter;
            float iou = inter / fmaxf(uni, 1e-12f);
            unsigned long long bits = __ballot(iou > NMS_THR);
            if (lane == 0) M[i][wd] = bits;
        }
    }
    __syncthreads();

    // greedy NMS: wave 0, M rows pre-distributed across lanes, readlane core.
    // Only accumulate suppression into current/future words (past words dead).
    if (wv == 0) {
        unsigned long long acc[NWORDS] = {0, 0, 0, 0, 0, 0, 0};
        unsigned long long keepw[NWORDS];
#pragma unroll
        for (int iw = 0; iw < NWORDS; ++iw) {
            unsigned long long mrow[NWORDS];
#pragma unroll
            for (int w = iw; w < NWORDS; ++w) mrow[w] = M[iw * 64 + lane][w];
            unsigned long long sup = acc[iw];
            unsigned long long K = 0;
            int nb = (iw == NWORDS - 1) ? (NCAND - 64 * (NWORDS - 1)) : 64;
            for (int ib = 0; ib < nb; ++ib) {
                if (!((sup >> ib) & 1ull)) {
                    K |= (1ull << ib);
                    int lo, hi;
                    lo = __builtin_amdgcn_readlane((int)(unsigned)mrow[iw], ib);
                    hi = __builtin_amdgcn_readlane((int)(unsigned)(mrow[iw] >> 32), ib);
                    sup |= ((unsigned long long)(unsigned)hi << 32) | (unsigned)lo;
#pragma unroll
                    for (int w = iw + 1; w < NWORDS; ++w) {
                        lo = __builtin_amdgcn_readlane((int)(unsigned)mrow[w], ib);
                        hi = __builtin_amdgcn_readlane((int)(unsigned)(mrow[w] >> 32), ib);
                        acc[w] |= ((unsigned long long)(unsigned)hi << 32) | (unsigned)lo;
                    }
                }
            }
            keepw[iw] = K;
        }
        if (lane == 0) {
            int a = 0;
#pragma unroll
            for (int w = 0; w < NWORDS; ++w) {
                keepw_s[w] = keepw[w];
                wpre_s[w] = a;
                a += __popcll(keepw[w]);
            }
            wpre_s[NWORDS] = a;
        }
    }
    __syncthreads();

    // kidx: kept (ascending) then unkept (ascending)
    if (tid < NCAND) {
        int w = tid >> 6, bb = tid & 63;
        unsigned long long kwv = keepw_s[w];
        bool kp = (kwv >> bb) & 1ull;
        unsigned long long below_mask = (bb == 0) ? 0ull : (~0ull >> (64 - bb));
        int below = wpre_s[w] + __popcll(kwv & below_mask);
        int nkept = wpre_s[NWORDS];
        int pos = kp ? below : nkept + (tid - below);
        if (pos < NOUT) kidx[pos] = tid;
    }
    __syncthreads();

    if (tid < NOUT) {
        int i = kidx[tid];
        bool kp = (keepw_s[i >> 6] >> (i & 63)) & 1ull;
        float* ob = out + ((size_t)img * NOUT + tid) * 4;
        ob[0] = x1[i];
        ob[1] = y1[i];
        ob[2] = x2[i];
        ob[3] = y2[i];
        out[(size_t)BATCH * NOUT * 4 + (size_t)img * NOUT + tid] = (float)lab[i];
        out[(size_t)BATCH * NOUT * 4 + (size_t)BATCH * NOUT + (size_t)img * NOUT + tid] =
            kp ? scs[i] : -INFINITY;
    }
}

extern "C" void kernel_launch(void* const* d_in, const int* in_sizes, int n_in,
                              void* d_out, int out_size, void* d_ws, size_t ws_size,
                              hipStream_t stream) {
    const float* logits = (const float*)d_in[0];
    const float* bbox = (const float*)d_in[1];
    const float* priors = (const float*)d_in[2];
    float* out = (float*)d_out;
    char* ws = (char*)d_ws;

    unsigned* hist = (unsigned*)(ws + OFF_HIST);
    unsigned* cnt = (unsigned*)(ws + OFF_CNT);
    unsigned long long* cand = (unsigned long long*)(ws + OFF_CAND);

    hipMemsetAsync(ws, 0, OFF_CNT, stream);  // zero hist only (cnt fully written)

    dim3 g1(P / RPB, BATCH);
    k_hist<<<g1, 256, 0, stream>>>(logits, hist, cnt, cand);
    k_post<<<BATCH, 1024, 0, stream>>>(bbox, priors, hist, cnt, cand, out);
}